// Round 19
// baseline (211.346 us; speedup 1.0000x reference)
//
#include <hip/hip_runtime.h>
#include <math.h>

#define NB 2048
#define NT 512
#define ND 64

typedef float    f32x4 __attribute__((ext_vector_type(4)));
typedef short    s16x8 __attribute__((ext_vector_type(8)));

#define MFMA32(A,B,C) __builtin_amdgcn_mfma_f32_16x16x32_bf16((A),(B),(C),0,0,0)

#if __has_builtin(__builtin_amdgcn_exp2f)
#define EXP2F(x) __builtin_amdgcn_exp2f(x)
#else
#define EXP2F(x) __expf((x) * 0.6931471805599453f)
#endif
#if __has_builtin(__builtin_amdgcn_logf)
#define LOG2F(x) __builtin_amdgcn_logf(x)
#else
#define LOG2F(x) (__logf(x) * 1.4426950408889634f)
#endif
#if __has_builtin(__builtin_amdgcn_rcpf)
#define RCPF(x) __builtin_amdgcn_rcpf(x)
#else
#define RCPF(x) __fdividef(1.0f, (x))
#endif

// Pure-C bf16 round-to-nearest-even -- init-time only.
__device__ __forceinline__ unsigned short bf16rn(float f) {
  unsigned u = __float_as_uint(f);
  unsigned r = u + 0x7FFFu + ((u >> 16) & 1u);
  return (unsigned short)(r >> 16);
}
__device__ __forceinline__ unsigned pack2(float a, float b) {
  return (unsigned)bf16rn(a) | ((unsigned)bf16rn(b) << 16);
}
// Truncating bf16 pack (proven shift/and form; NOT v_perm -- see R10).
__device__ __forceinline__ unsigned pack2t(float a, float b) {
  return (__float_as_uint(a) >> 16) | (__float_as_uint(b) & 0xFFFF0000u);
}

union frag8 { s16x8 s8; unsigned u[4]; };

// pack D-layout f32x4 into a zero-padded MFMA32 A-frag (k = 8*(lane>>4)+i).
__device__ __forceinline__ s16x8 pack8t(f32x4 x) {
  frag8 r;
  r.u[0] = pack2t(x[0], x[1]);
  r.u[1] = pack2t(x[2], x[3]);
  r.u[2] = 0u; r.u[3] = 0u;
  return r.s8;
}

// ---------------------------------------------------------------------------
// Merged init + sort (single launch; block 12 = sort, blocks 0-11 = init).
// ws: [0,32K) W frags, [32K,48K) base frags, [48K,56K) partials, [56K,64K) perm
// ---------------------------------------------------------------------------
__global__ void fhmm_init_sort(const float* __restrict__ py,
                               const int* __restrict__ lengths,
                               unsigned short* __restrict__ ws16,
                               float* __restrict__ partials,
                               int* __restrict__ perm)
{
  const float LOG2E = 1.4426950408889634f;
  if (blockIdx.x == 12) {              // ---- sort block ----
    __shared__ int hist[512];
    __shared__ int cnt[512];
    __shared__ int sa[512], sb2[512];
    const int tid = threadIdx.x;
    hist[tid] = 0; hist[tid + 256] = 0;
    cnt[tid] = 0;  cnt[tid + 256] = 0;
    __syncthreads();
    int myb[8];
#pragma unroll
    for (int u = 0; u < 8; ++u) {
      int i = tid + 256 * u;
      myb[u] = 512 - lengths[i];
      atomicAdd(&hist[myb[u]], 1);
    }
    __syncthreads();
    sa[tid] = hist[tid]; sa[tid + 256] = hist[tid + 256];
    __syncthreads();
    int* src = sa; int* dst = sb2;
    for (int off = 1; off < 512; off <<= 1) {
      for (int k = tid; k < 512; k += 256)
        dst[k] = src[k] + ((k >= off) ? src[k - off] : 0);
      __syncthreads();
      int* tp = src; src = dst; dst = tp;
    }
#pragma unroll
    for (int u = 0; u < 8; ++u) {
      int i = tid + 256 * u;
      int b2 = myb[u];
      int pos = src[b2] - hist[b2] + atomicAdd(&cnt[b2], 1);
      perm[pos] = i;
    }
    return;
  }
  int t = blockIdx.x * 256 + threadIdx.x;
  if (t < 2048) partials[t] = 0.f;
  if (t < 2048) {
    int st = t >> 7, kk = (t >> 6) & 1, l = t & 63;
    int rho = st * 16 + (l & 15);
    int s = (4 * (rho >> 6) + (rho & 3)) * 16 + ((rho >> 2) & 15);
    int d0 = kk * 32 + 8 * (l >> 4);
    unsigned short* dst = ws16 + (size_t)t * 8;
#pragma unroll
    for (int i = 0; i < 8; ++i) {
      float p = py[s * 64 + d0 + i];
      dst[i] = bf16rn((logf(p) - log1pf(-p)) * LOG2E);
    }
  } else if (t < 3072) {
    int t2 = t - 2048;
    int st = t2 >> 6, l = t2 & 63;
    unsigned short v[8] = {0, 0, 0, 0, 0, 0, 0, 0};
    if (l < 16) {
      int rho = st * 16 + l;
      int s = (4 * (rho >> 6) + (rho & 3)) * 16 + ((rho >> 2) & 15);
      float base = 0.f;
      for (int d = 0; d < 64; ++d) base += log1pf(-py[s * 64 + d]);
      base *= LOG2E;
      unsigned short hi = bf16rn(base);
      float basehi = __uint_as_float(((unsigned)hi) << 16);
      v[0] = hi;
      v[1] = bf16rn(base - basehi);
    }
    unsigned short* dst = ws16 + (size_t)(2048 + t2) * 8;
#pragma unroll
    for (int i = 0; i < 8; ++i) dst[i] = v[i];
  }
}

// ---------------------------------------------------------------------------
// Forward-backward split kernel: 1024 blocks x 4 waves = 4096 waves
// (2048 seqs x 2 halves) -> 4 waves/SIMD (2x the latency hiding of R16).
// Wave roles: wv&1==0 -> FORWARD over [0,mid); wv&1==1 -> BACKWARD over
// [mid,len) from r=1 (beta recursion: r' = Tw (r.E_t) Tx^T, via the same
// MFMA free-transpose chain with TRANSPOSED Tw/Tx B-frags).  L is later
// combined as Sf + Sb + log2(alpha_mid . beta_mid).  bf16 G (R8-proven,
// 8KB/wave) so LDS = 32KB/block -> 4 blocks/CU.  Block remap lb makes each
// CU's 4 co-resident blocks' rank-sum constant (balanced work).
// SCALE-ORDER INVARIANT maintained (no product of two tiny factors).
// ---------------------------------------------------------------------------
__global__ __launch_bounds__(256, 4) void fhmm_fwd3(
    const int* __restrict__ seq, const int* __restrict__ lengths,
    const float* __restrict__ pw, const float* __restrict__ px,
    const void* __restrict__ wfrag, const int* __restrict__ perm,
    float* __restrict__ alphaM, float* __restrict__ betaM,
    float* __restrict__ scal)
{
  __shared__ uint2 e_lds[4][1024];   // 8KB per wave (bf16 G), 32KB total

  const int tid = threadIdx.x;
  const int wv = tid >> 6, j = tid & 63;
  const int q = j >> 4, tl = j & 15;
  const int bid = blockIdx.x;
  const int lb  = (bid < 512) ? bid : (1535 - bid);  // per-CU rank-sum const
  const int rank = 2 * lb + (wv >> 1);
  const int h = wv & 1;                              // 0 = fwd, 1 = bwd
  const int b = perm[rank];
  if (b < 0 || b >= NB) return;
  uint2* e_w = e_lds[wv];
  const s16x8* wf_g = (const s16x8*)wfrag;
  const s16x8* w2_g = wf_g + 2048;

  // B-frags: fwd b[i] = T[4q+i][tl]; bwd (transposed) b[i] = T[tl][4q+i].
  s16x8 twb8, txb8;
  {
    frag8 a, c;
    if (h == 0) {
      a.u[0] = pack2(pw[(4 * q + 0) * 16 + tl], pw[(4 * q + 1) * 16 + tl]);
      a.u[1] = pack2(pw[(4 * q + 2) * 16 + tl], pw[(4 * q + 3) * 16 + tl]);
      c.u[0] = pack2(px[(4 * q + 0) * 16 + tl], px[(4 * q + 1) * 16 + tl]);
      c.u[1] = pack2(px[(4 * q + 2) * 16 + tl], px[(4 * q + 3) * 16 + tl]);
    } else {
      a.u[0] = pack2(pw[tl * 16 + 4 * q + 0], pw[tl * 16 + 4 * q + 1]);
      a.u[1] = pack2(pw[tl * 16 + 4 * q + 2], pw[tl * 16 + 4 * q + 3]);
      c.u[0] = pack2(px[tl * 16 + 4 * q + 0], px[tl * 16 + 4 * q + 1]);
      c.u[1] = pack2(px[tl * 16 + 4 * q + 2], px[tl * 16 + 4 * q + 3]);
    }
    a.u[2] = 0u; a.u[3] = 0u; c.u[2] = 0u; c.u[3] = 0u;
    twb8 = a.s8; txb8 = c.s8;
  }

  s16x8 f2 = {0, 0, 0, 0, 0, 0, 0, 0};   // ones in k-rows 0,1 (base column)
  if (q == 0) { f2[0] = (short)0x3F80; f2[1] = (short)0x3F80; }

  s16x8 ones8;                            // all-ones B (sum collapser)
  {
    frag8 o;
    o.u[0] = 0x3F803F80u; o.u[1] = 0x3F803F80u;
    o.u[2] = 0x3F803F80u; o.u[3] = 0x3F803F80u;
    ones8 = o.s8;
  }

  const int len = lengths[b];
  const int mid = len >> 1;
  const int* ybase = seq + (size_t)b * NT * ND;
  const f32x4 z4 = {0.f, 0.f, 0.f, 0.f};

  f32x4 p;
  if (h == 0) { p = z4; if (j == 0) p[0] = 1.f; }   // alpha0 = delta(0,0)
  else { p[0] = 1.f; p[1] = 1.f; p[2] = 1.f; p[3] = 1.f; }  // beta_len = 1

  float L2 = 0.f, Ls = 0.f, R = 0.f;

  for (int k = 0;; ++k) {
    int t_lo, ns;
    if (h == 0) {
      t_lo = 16 * k;
      if (t_lo >= mid) break;
      ns = mid - t_lo; if (ns > 16) ns = 16;
    } else {
      int t_hi = len - 16 * k;
      if (t_hi <= mid) break;
      t_lo = t_hi - 16; if (t_lo < mid) t_lo = mid;
      ns = t_hi - t_lo;
    }

    // ---- load y rows t_lo+tl (clamped), build bf16 0/1 B-frags ----
    s16x8 f0, f1;
    {
      int row = t_lo + tl;
      if (row > len - 1) row = len - 1;
      const int* yr = ybase + (size_t)row * ND + 8 * q;
      const int4 ya0 = ((const int4*)yr)[0];
      const int4 ya1 = ((const int4*)yr)[1];
      const int4 yb0 = ((const int4*)(yr + 32))[0];
      const int4 yb1 = ((const int4*)(yr + 32))[1];
      frag8 f0u, f1u;
      f0u.u[0] = (ya0.x ? 0x3F80u : 0u) | (ya0.y ? 0x3F800000u : 0u);
      f0u.u[1] = (ya0.z ? 0x3F80u : 0u) | (ya0.w ? 0x3F800000u : 0u);
      f0u.u[2] = (ya1.x ? 0x3F80u : 0u) | (ya1.y ? 0x3F800000u : 0u);
      f0u.u[3] = (ya1.z ? 0x3F80u : 0u) | (ya1.w ? 0x3F800000u : 0u);
      f1u.u[0] = (yb0.x ? 0x3F80u : 0u) | (yb0.y ? 0x3F800000u : 0u);
      f1u.u[1] = (yb0.z ? 0x3F80u : 0u) | (yb0.w ? 0x3F800000u : 0u);
      f1u.u[2] = (yb1.x ? 0x3F80u : 0u) | (yb1.y ? 0x3F800000u : 0u);
      f1u.u[3] = (yb1.z ? 0x3F80u : 0u) | (yb1.w ? 0x3F800000u : 0u);
      f0 = f0u.s8; f1 = f1u.s8;
    }

    // ---- emission: G = exp2(E - R) incl. base, bf16, 3 MFMAs/st ----
#pragma unroll
    for (int st = 0; st < 16; ++st) {
      f32x4 acc = MFMA32(w2_g[st * 64 + j], f2, z4);
      acc = MFMA32(wf_g[(2 * st + 0) * 64 + j], f0, acc);
      acc = MFMA32(wf_g[(2 * st + 1) * 64 + j], f1, acc);
      float G0 = EXP2F(fminf(acc[0] - R, 80.f));
      float G1 = EXP2F(fminf(acc[1] - R, 80.f));
      float G2 = EXP2F(fminf(acc[2] - R, 80.f));
      float G3 = EXP2F(fminf(acc[3] - R, 80.f));
      e_w[tl * 64 + ((st * 4 + q) ^ tl)] = make_uint2(pack2t(G0, G1), pack2t(G2, G3));
    }

    // ---- recursion (direction-dependent; 1-deep G prefetch) ----
    float LsC = 0.f;
    if (h == 0) {
      uint2 ev = e_w[j];                 // slot it=0
      for (int it = 0; it < ns; ++it) {
        const uint2 ec = ev;
        const int itn = (it + 1) & 15;
        ev = e_w[itn * 64 + (j ^ itn)];
        f32x4 g;
        g[0] = __uint_as_float(ec.x << 16);
        g[1] = __uint_as_float(ec.x & 0xFFFF0000u);
        g[2] = __uint_as_float(ec.y << 16);
        g[3] = __uint_as_float(ec.y & 0xFFFF0000u);
        s16x8 vb = pack8t(p);
        f32x4 P  = MFMA32(vb, twb8, z4);
        f32x4 S1 = MFMA32(vb, ones8, z4);
        f32x4 U  = MFMA32(pack8t(P), txb8, z4);
        f32x4 S2 = MFMA32(pack8t(S1), ones8, z4);
        const float s   = fmaxf(S2[0], 1e-30f);
        const float inv = RCPF(s);
        LsC += LOG2F(s);
        p[0] = (U[0] * inv) * g[0];
        p[1] = (U[1] * inv) * g[1];
        p[2] = (U[2] * inv) * g[2];
        p[3] = (U[3] * inv) * g[3];
      }
    } else {
      int it0 = ns - 1;
      uint2 ev = e_w[it0 * 64 + (j ^ it0)];
      for (int it = it0; it >= 0; --it) {
        const uint2 ec = ev;
        const int itn = (it - 1) & 15;
        ev = e_w[itn * 64 + (j ^ itn)];
        f32x4 u4;
        u4[0] = p[0] * __uint_as_float(ec.x << 16);
        u4[1] = p[1] * __uint_as_float(ec.x & 0xFFFF0000u);
        u4[2] = p[2] * __uint_as_float(ec.y << 16);
        u4[3] = p[3] * __uint_as_float(ec.y & 0xFFFF0000u);
        s16x8 vb = pack8t(u4);
        f32x4 P  = MFMA32(vb, twb8, z4);
        f32x4 S1 = MFMA32(vb, ones8, z4);
        f32x4 U  = MFMA32(pack8t(P), txb8, z4);
        f32x4 S2 = MFMA32(pack8t(S1), ones8, z4);
        const float s   = fmaxf(S2[0], 1e-30f);
        const float inv = RCPF(s);
        LsC += LOG2F(s);
        p[0] = U[0] * inv;
        p[1] = U[1] * inv;
        p[2] = U[2] * inv;
        p[3] = U[3] * inv;
      }
    }
    L2 += (float)ns * R;
    Ls += LsC;
    R  += LsC * 0.0625f;
  }

  // write half-state + scale (same lane/reg -> slot mapping both halves)
  {
    float* outv = (h ? betaM : alphaM) + (size_t)b * 256 + j * 4;
    *(f32x4*)outv = p;
    if (j == 0) scal[2 * b + h] = L2 + Ls;
  }
}

// ---------------------------------------------------------------------------
// Combine: partials[b] = (Sf + Sb + log2(alpha_mid . beta_mid)) * ln2.
// ---------------------------------------------------------------------------
__global__ void fhmm_combine(const float* __restrict__ alphaM,
                             const float* __restrict__ betaM,
                             const float* __restrict__ scal,
                             float* __restrict__ partials)
{
  const int b = blockIdx.x, tid = threadIdx.x;
  float v = alphaM[(size_t)b * 256 + tid] * betaM[(size_t)b * 256 + tid];
#pragma unroll
  for (int off = 1; off < 64; off <<= 1) v += __shfl_xor(v, off);
  __shared__ float red[4];
  if ((tid & 63) == 0) red[tid >> 6] = v;
  __syncthreads();
  if (tid == 0) {
    float dot = fmaxf((red[0] + red[1]) + (red[2] + red[3]), 1e-35f);
    partials[b] = (scal[2 * b] + scal[2 * b + 1] + LOG2F(dot))
                  * 0.6931471805599453f;
  }
}

// ---------------------------------------------------------------------------
// Fallback main (EXACT R16 kernel, proven 180us / absmax 0.0).
// ---------------------------------------------------------------------------
__global__ __launch_bounds__(256, 2) void fhmm_fwd2(
    const int* __restrict__ seq, const int* __restrict__ lengths,
    const float* __restrict__ pw, const float* __restrict__ px,
    const void* __restrict__ wfrag, const int* __restrict__ perm,
    float* __restrict__ partials)
{
  __shared__ f32x4 e_lds[4][1024];

  const int tid = threadIdx.x;
  const int wv = tid >> 6, j = tid & 63;
  const int q = j >> 4, tl = j & 15;
  const int bid = blockIdx.x;
  const int lb  = (bid < 256) ? bid : (767 - bid);
  const int b = perm[(lb << 2) | wv];
  if (b < 0 || b >= NB) return;
  f32x4* e_w = e_lds[wv];
  const s16x8* wf_g = (const s16x8*)wfrag;
  const s16x8* w2_g = wf_g + 2048;

  s16x8 twb8, txb8;
  {
    frag8 a, c;
    a.u[0] = pack2(pw[(4 * q + 0) * 16 + tl], pw[(4 * q + 1) * 16 + tl]);
    a.u[1] = pack2(pw[(4 * q + 2) * 16 + tl], pw[(4 * q + 3) * 16 + tl]);
    a.u[2] = 0u; a.u[3] = 0u;
    c.u[0] = pack2(px[(4 * q + 0) * 16 + tl], px[(4 * q + 1) * 16 + tl]);
    c.u[1] = pack2(px[(4 * q + 2) * 16 + tl], px[(4 * q + 3) * 16 + tl]);
    c.u[2] = 0u; c.u[3] = 0u;
    twb8 = a.s8; txb8 = c.s8;
  }

  s16x8 f2 = {0, 0, 0, 0, 0, 0, 0, 0};
  if (q == 0) { f2[0] = (short)0x3F80; f2[1] = (short)0x3F80; }

  s16x8 ones8;
  {
    frag8 o;
    o.u[0] = 0x3F803F80u; o.u[1] = 0x3F803F80u;
    o.u[2] = 0x3F803F80u; o.u[3] = 0x3F803F80u;
    ones8 = o.s8;
  }

  f32x4 p = {0.f, 0.f, 0.f, 0.f};
  if (j == 0) p[0] = 1.f;

  const int len = lengths[b];
  const int* ybase = seq + (size_t)b * NT * ND;

  int4 ya0, ya1, yb0, yb1;
  {
    const int* yr = ybase + (size_t)tl * ND + 8 * q;
    ya0 = ((const int4*)yr)[0]; ya1 = ((const int4*)yr)[1];
    yb0 = ((const int4*)(yr + 32))[0]; yb1 = ((const int4*)(yr + 32))[1];
  }

  float L2 = 0.f, Ls = 0.f, R = 0.f;
  const f32x4 z4 = {0.f, 0.f, 0.f, 0.f};

  for (int t0 = 0; t0 < len; t0 += 16) {
    frag8 f0u, f1u;
    f0u.u[0] = (ya0.x ? 0x3F80u : 0u) | (ya0.y ? 0x3F800000u : 0u);
    f0u.u[1] = (ya0.z ? 0x3F80u : 0u) | (ya0.w ? 0x3F800000u : 0u);
    f0u.u[2] = (ya1.x ? 0x3F80u : 0u) | (ya1.y ? 0x3F800000u : 0u);
    f0u.u[3] = (ya1.z ? 0x3F80u : 0u) | (ya1.w ? 0x3F800000u : 0u);
    f1u.u[0] = (yb0.x ? 0x3F80u : 0u) | (yb0.y ? 0x3F800000u : 0u);
    f1u.u[1] = (yb0.z ? 0x3F80u : 0u) | (yb0.w ? 0x3F800000u : 0u);
    f1u.u[2] = (yb1.x ? 0x3F80u : 0u) | (yb1.y ? 0x3F800000u : 0u);
    f1u.u[3] = (yb1.z ? 0x3F80u : 0u) | (yb1.w ? 0x3F800000u : 0u);
    const s16x8 f0 = f0u.s8, f1 = f1u.s8;

    if (t0 + 16 < len) {
      const int* yr = ybase + (size_t)(t0 + 16 + tl) * ND + 8 * q;
      ya0 = ((const int4*)yr)[0]; ya1 = ((const int4*)yr)[1];
      yb0 = ((const int4*)(yr + 32))[0]; yb1 = ((const int4*)(yr + 32))[1];
    }

#pragma unroll
    for (int st = 0; st < 16; ++st) {
      f32x4 acc = MFMA32(w2_g[st * 64 + j], f2, z4);
      acc = MFMA32(wf_g[(2 * st + 0) * 64 + j], f0, acc);
      acc = MFMA32(wf_g[(2 * st + 1) * 64 + j], f1, acc);
      f32x4 G;
      G[0] = EXP2F(fminf(acc[0] - R, 80.f));
      G[1] = EXP2F(fminf(acc[1] - R, 80.f));
      G[2] = EXP2F(fminf(acc[2] - R, 80.f));
      G[3] = EXP2F(fminf(acc[3] - R, 80.f));
      e_w[tl * 64 + ((st * 4 + q) ^ tl)] = G;
    }

    const int nsteps = (len - t0 < 16) ? (len - t0) : 16;
    float LsC = 0.f;
    f32x4 gv = e_w[j];
    for (int it = 0; it < nsteps; ++it) {
      const f32x4 g = gv;
      const int itn = (it + 1) & 15;
      gv = e_w[itn * 64 + (j ^ itn)];
      s16x8 vb = pack8t(p);
      f32x4 P  = MFMA32(vb, twb8, z4);
      f32x4 S1 = MFMA32(vb, ones8, z4);
      f32x4 U  = MFMA32(pack8t(P), txb8, z4);
      f32x4 S2 = MFMA32(pack8t(S1), ones8, z4);
      const float s   = fmaxf(S2[0], 1e-30f);
      const float inv = RCPF(s);
      LsC += LOG2F(s);
      f32x4 pn;
      pn[0] = (U[0] * inv) * g[0];
      pn[1] = (U[1] * inv) * g[1];
      pn[2] = (U[2] * inv) * g[2];
      pn[3] = (U[3] * inv) * g[3];
      p = pn;
    }
    L2 += (float)nsteps * R;
    Ls += LsC;
    R  += LsC * 0.0625f;
  }
  {
    f32x4 F1 = MFMA32(pack8t(p), ones8, z4);
    f32x4 F2 = MFMA32(pack8t(F1), ones8, z4);
    float sf = fmaxf(F2[0], 1e-35f);
    float L = (L2 + Ls + LOG2F(sf)) * 0.6931471805599453f;
    if (j == 0) partials[b] = L;
  }
}

// ---------------------------------------------------------------------------
// Round-1 fallback (block per sequence) for small workspace.
// ---------------------------------------------------------------------------
__global__ __launch_bounds__(256, 3) void fhmm_fwd1(
    const int* __restrict__ seq, const int* __restrict__ lengths,
    const float* __restrict__ pw, const float* __restrict__ px,
    const float* __restrict__ py, float* __restrict__ partials,
    float* __restrict__ out)
{
  const int b = blockIdx.x, tid = threadIdx.x;
  const int wp = tid >> 4, xc = tid & 15;
  float Twc[16], Txc[16], W[64], base = 0.f;
#pragma unroll
  for (int w = 0; w < 16; ++w) Twc[w] = pw[w * 16 + wp];
#pragma unroll
  for (int x = 0; x < 16; ++x) Txc[x] = px[x * 16 + xc];
#pragma unroll
  for (int d = 0; d < 64; ++d) {
    float pv = py[tid * 64 + d];
    W[d] = logf(pv) - log1pf(-pv);
    base += log1pf(-pv);
  }
  __shared__ __align__(16) float yf[64];
  __shared__ __align__(16) float v_s[256];
  __shared__ __align__(16) float tmp_s[256];
  __shared__ float red[8];
  const int len = lengths[b];
  const int* yb = seq + (size_t)b * (NT * ND);
  v_s[tid] = (tid == 0) ? 1.f : 0.f;
  float L = 0.f, ynext = 0.f;
  if (tid < 64) ynext = (float)yb[tid];
  for (int t = 0; t < len; ++t) {
    if (tid < 64) yf[tid] = ynext;
    __syncthreads();
    if (tid < 64 && (t + 1) < len) ynext = (float)yb[(t + 1) * ND + tid];
    float e0 = base, e1 = 0.f, e2 = 0.f, e3 = 0.f;
    const float4* y4p = (const float4*)yf;
#pragma unroll
    for (int i = 0; i < 16; ++i) {
      float4 y4 = y4p[i];
      e0 = fmaf(y4.x, W[4 * i + 0], e0); e1 = fmaf(y4.y, W[4 * i + 1], e1);
      e2 = fmaf(y4.z, W[4 * i + 2], e2); e3 = fmaf(y4.w, W[4 * i + 3], e3);
    }
    float e = (e0 + e1) + (e2 + e3);
    float s1a = 0.f, s1b = 0.f;
#pragma unroll
    for (int w = 0; w < 16; w += 2) {
      s1a = fmaf(Twc[w], v_s[w * 16 + xc], s1a);
      s1b = fmaf(Twc[w + 1], v_s[(w + 1) * 16 + xc], s1b);
    }
    tmp_s[tid] = s1a + s1b;
    float mm = e;
#pragma unroll
    for (int off = 32; off; off >>= 1) mm = fmaxf(mm, __shfl_xor(mm, off));
    if ((tid & 63) == 0) red[tid >> 6] = mm;
    __syncthreads();
    mm = fmaxf(fmaxf(red[0], red[1]), fmaxf(red[2], red[3]));
    float q0 = 0.f, q1 = 0.f;
    const float4* t4p = (const float4*)(tmp_s + wp * 16);
#pragma unroll
    for (int i = 0; i < 4; ++i) {
      float4 t4 = t4p[i];
      q0 = fmaf(t4.x, Txc[4 * i + 0], q0); q1 = fmaf(t4.y, Txc[4 * i + 1], q1);
      q0 = fmaf(t4.z, Txc[4 * i + 2], q0); q1 = fmaf(t4.w, Txc[4 * i + 3], q1);
    }
    float val = (q0 + q1) * __expf(e - mm);
    float s = val;
#pragma unroll
    for (int off = 32; off; off >>= 1) s += __shfl_xor(s, off);
    if ((tid & 63) == 0) red[4 + (tid >> 6)] = s;
    __syncthreads();
    s = (red[4] + red[5]) + (red[6] + red[7]);
    L += __logf(s) + mm;
    v_s[tid] = val * (1.0f / s);
  }
  if (partials) { if (tid == 0) partials[b] = L; }
  else { if (tid == 0) atomicAdd(out, L); }
}

// ---------------------------------------------------------------------------
// Finalize: deterministic tree-sum of per-sequence LLs + priors.
// ---------------------------------------------------------------------------
__global__ void fhmm_finalize(const float* __restrict__ partials,
                              const float* __restrict__ pw,
                              const float* __restrict__ px,
                              const float* __restrict__ py,
                              float* __restrict__ out)
{
  const int tid = threadIdx.x;
  float a = 0.f;
  if (partials) {
#pragma unroll
    for (int i = 0; i < 8; ++i) a += partials[tid + 256 * i];
  }
  {
    int i = tid >> 4, j = tid & 15;
    if (i != j) a += -0.9f * (logf(pw[tid]) + logf(px[tid]));
  }
  for (int k = 0; k < 64; ++k) {
    float p = py[tid * 64 + k];
    a += -0.9f * logf(p) - 0.1f * log1pf(-p);
  }
  __shared__ float red[256];
  red[tid] = a;
  __syncthreads();
  for (int s = 128; s > 0; s >>= 1) {
    if (tid < s) red[tid] += red[tid + s];
    __syncthreads();
  }
  if (tid == 0) {
    const float cst =
        2.f * (16.f * 0.2846828704729192f - 240.f * 2.2527126517342055f)
        - (2.2527126517342055f + 0.0663762397347443f) * 16384.f;
    out[0] = red[0] + cst;
  }
}

extern "C" void kernel_launch(void* const* d_in, const int* in_sizes, int n_in,
                              void* d_out, int out_size, void* d_ws, size_t ws_size,
                              hipStream_t stream) {
  const int*   seq = (const int*)d_in[0];
  const int*   len = (const int*)d_in[1];
  const float* pw  = (const float*)d_in[2];
  const float* px  = (const float*)d_in[3];
  const float* py  = (const float*)d_in[4];
  float*       out = (float*)d_out;

  const size_t NEED1 = 65536;  // 32K wfrag + 16K base + 8K partials + 8K perm
  const size_t NEED2 = NEED1 + (size_t)2 * NB * 256 * 4 + NB * 2 * 4;  // +4.2MB
  if (ws_size >= NEED2) {
    unsigned short* wf = (unsigned short*)d_ws;
    float* partials = (float*)((char*)d_ws + 49152);
    int*   perm     = (int*)((char*)d_ws + 57344);
    float* alphaM   = (float*)((char*)d_ws + 65536);
    float* betaM    = alphaM + (size_t)NB * 256;
    float* scal     = betaM + (size_t)NB * 256;
    fhmm_init_sort<<<13, 256, 0, stream>>>(py, len, wf, partials, perm);
    fhmm_fwd3<<<1024, 256, 0, stream>>>(seq, len, pw, px, (const void*)wf,
                                        perm, alphaM, betaM, scal);
    fhmm_combine<<<NB, 256, 0, stream>>>(alphaM, betaM, scal, partials);
    fhmm_finalize<<<1, 256, 0, stream>>>(partials, pw, px, py, out);
  } else if (ws_size >= NEED1) {
    unsigned short* wf = (unsigned short*)d_ws;
    float* partials = (float*)((char*)d_ws + 49152);
    int*   perm     = (int*)((char*)d_ws + 57344);
    fhmm_init_sort<<<13, 256, 0, stream>>>(py, len, wf, partials, perm);
    fhmm_fwd2<<<512, 256, 0, stream>>>(seq, len, pw, px, (const void*)wf, perm, partials);
    fhmm_finalize<<<1, 256, 0, stream>>>(partials, pw, px, py, out);
  } else if (ws_size >= NB * sizeof(float)) {
    float* partials = (float*)d_ws;
    fhmm_fwd1<<<NB, 256, 0, stream>>>(seq, len, pw, px, py, partials, out);
    fhmm_finalize<<<1, 256, 0, stream>>>(partials, pw, px, py, out);
  } else {
    fhmm_finalize<<<1, 256, 0, stream>>>(nullptr, pw, px, py, out);
    fhmm_fwd1<<<NB, 256, 0, stream>>>(seq, len, pw, px, py, nullptr, out);
  }
}

// Round 21
// 200.492 us; speedup vs baseline: 1.0541x; 1.0541x over previous
//
#include <hip/hip_runtime.h>
#include <math.h>

#define NB 2048
#define NT 512
#define ND 64

typedef float    f32x4 __attribute__((ext_vector_type(4)));
typedef short    s16x8 __attribute__((ext_vector_type(8)));

#define MFMA32(A,B,C) __builtin_amdgcn_mfma_f32_16x16x32_bf16((A),(B),(C),0,0,0)

#if __has_builtin(__builtin_amdgcn_exp2f)
#define EXP2F(x) __builtin_amdgcn_exp2f(x)
#else
#define EXP2F(x) __expf((x) * 0.6931471805599453f)
#endif
#if __has_builtin(__builtin_amdgcn_logf)
#define LOG2F(x) __builtin_amdgcn_logf(x)
#else
#define LOG2F(x) (__logf(x) * 1.4426950408889634f)
#endif
#if __has_builtin(__builtin_amdgcn_rcpf)
#define RCPF(x) __builtin_amdgcn_rcpf(x)
#else
#define RCPF(x) __fdividef(1.0f, (x))
#endif

// Pure-C bf16 round-to-nearest-even -- init-time only.
__device__ __forceinline__ unsigned short bf16rn(float f) {
  unsigned u = __float_as_uint(f);
  unsigned r = u + 0x7FFFu + ((u >> 16) & 1u);
  return (unsigned short)(r >> 16);
}
__device__ __forceinline__ unsigned pack2(float a, float b) {
  return (unsigned)bf16rn(a) | ((unsigned)bf16rn(b) << 16);
}
// Truncating bf16 pack (proven shift/and form; NOT v_perm -- see R10).
__device__ __forceinline__ unsigned pack2t(float a, float b) {
  return (__float_as_uint(a) >> 16) | (__float_as_uint(b) & 0xFFFF0000u);
}

union frag8 { s16x8 s8; unsigned u[4]; };

// pack D-layout f32x4 into a zero-padded MFMA32 A-frag (k = 8*(lane>>4)+i).
__device__ __forceinline__ s16x8 pack8t(f32x4 x) {
  frag8 r;
  r.u[0] = pack2t(x[0], x[1]);
  r.u[1] = pack2t(x[2], x[3]);
  r.u[2] = 0u; r.u[3] = 0u;
  return r.s8;
}

// ---------------------------------------------------------------------------
// Merged init + sort (single launch; block 12 = sort, blocks 0-11 = init).
// Init (R8 layout): bf16 A-frags of W2 = logit(probs_y)*log2(e), rows
// PERMUTED (rho -> s = (4*(rho>>6)+(rho&3))*16 + ((rho>>2)&15)); base frags
// bf16 hi+lo in k-slots 0/1 of the w2 block.  Zeroes partials.
// Sort: counting sort by DESCENDING length, parallel Hillis-Steele scan.
// ws: [0,32K) W frags, [32K,48K) base frags, [48K,56K) partials, [56K,64K) perm
// ---------------------------------------------------------------------------
__global__ void fhmm_init_sort(const float* __restrict__ py,
                               const int* __restrict__ lengths,
                               unsigned short* __restrict__ ws16,
                               float* __restrict__ partials,
                               int* __restrict__ perm)
{
  const float LOG2E = 1.4426950408889634f;
  if (blockIdx.x == 12) {              // ---- sort block ----
    __shared__ int hist[512];
    __shared__ int cnt[512];
    __shared__ int sa[512], sb2[512];
    const int tid = threadIdx.x;
    hist[tid] = 0; hist[tid + 256] = 0;
    cnt[tid] = 0;  cnt[tid + 256] = 0;
    __syncthreads();
    int myb[8];
#pragma unroll
    for (int u = 0; u < 8; ++u) {
      int i = tid + 256 * u;
      myb[u] = 512 - lengths[i];
      atomicAdd(&hist[myb[u]], 1);
    }
    __syncthreads();
    sa[tid] = hist[tid]; sa[tid + 256] = hist[tid + 256];
    __syncthreads();
    int* src = sa; int* dst = sb2;
    for (int off = 1; off < 512; off <<= 1) {
      for (int k = tid; k < 512; k += 256)
        dst[k] = src[k] + ((k >= off) ? src[k - off] : 0);
      __syncthreads();
      int* tp = src; src = dst; dst = tp;
    }
#pragma unroll
    for (int u = 0; u < 8; ++u) {
      int i = tid + 256 * u;
      int b2 = myb[u];
      int pos = src[b2] - hist[b2] + atomicAdd(&cnt[b2], 1);
      perm[pos] = i;
    }
    return;
  }
  int t = blockIdx.x * 256 + threadIdx.x;
  if (t < 2048) partials[t] = 0.f;
  if (t < 2048) {
    int st = t >> 7, kk = (t >> 6) & 1, l = t & 63;
    int rho = st * 16 + (l & 15);
    int s = (4 * (rho >> 6) + (rho & 3)) * 16 + ((rho >> 2) & 15);
    int d0 = kk * 32 + 8 * (l >> 4);
    unsigned short* dst = ws16 + (size_t)t * 8;
#pragma unroll
    for (int i = 0; i < 8; ++i) {
      float p = py[s * 64 + d0 + i];
      dst[i] = bf16rn((logf(p) - log1pf(-p)) * LOG2E);
    }
  } else if (t < 3072) {
    int t2 = t - 2048;
    int st = t2 >> 6, l = t2 & 63;
    unsigned short v[8] = {0, 0, 0, 0, 0, 0, 0, 0};
    if (l < 16) {
      int rho = st * 16 + l;
      int s = (4 * (rho >> 6) + (rho & 3)) * 16 + ((rho >> 2) & 15);
      float base = 0.f;
      for (int d = 0; d < 64; ++d) base += log1pf(-py[s * 64 + d]);
      base *= LOG2E;
      unsigned short hi = bf16rn(base);
      float basehi = __uint_as_float(((unsigned)hi) << 16);
      v[0] = hi;
      v[1] = bf16rn(base - basehi);
    }
    unsigned short* dst = ws16 + (size_t)(2048 + t2) * 8;
#pragma unroll
    for (int i = 0; i < 8; ++i) dst[i] = v[i];
  }
}

// ---------------------------------------------------------------------------
// Main (EXACT R16/R18 kernel -- converged optimum; 7.7x over baseline,
// absmax 0.0, twice reproduced at ~201us total).
// 256-thread blocks (4 waves), 512 blocks; complementary remap
// (bid<256 ? bid : 767-bid) -> uniform per-CU work.  Emission: G =
// exp2(E - R) incl. base, f32 in LDS (16KB/wave), 3 MFMAs/st.  Recursion:
// register-only MFMA free-transpose chain, COMPACT loop (R17's full unroll
// blew L1 I-cache: FETCH +18MB, -25% perf), 1-deep G prefetch, same-step
// ones-MFMA normalizer -- the 2-MFMA mass chain is REQUIRED for a
// wave-uniform normalizer (R20: single MFMA(pb,ones) gives per-row sums,
// breaks the telescope).  SCALE-ORDER INVARIANT: (U*inv) first, then *g
// (R10/R11: (U*g) first underflows f32 -> p collapses).
// ---------------------------------------------------------------------------
__global__ __launch_bounds__(256, 2) void fhmm_fwd2(
    const int* __restrict__ seq, const int* __restrict__ lengths,
    const float* __restrict__ pw, const float* __restrict__ px,
    const void* __restrict__ wfrag, const int* __restrict__ perm,
    float* __restrict__ partials)
{
  __shared__ f32x4 e_lds[4][1024];   // 16KB per wave: [16 steps][64 slots] f32x4

  const int tid = threadIdx.x;
  const int wv = tid >> 6, j = tid & 63;
  const int q = j >> 4, tl = j & 15;
  const int bid = blockIdx.x;
  const int lb  = (bid < 256) ? bid : (767 - bid);   // complementary (R8)
  const int b = perm[(lb << 2) | wv];
  if (b < 0 || b >= NB) return;
  f32x4* e_w = e_lds[wv];
  const s16x8* wf_g = (const s16x8*)wfrag;
  const s16x8* w2_g = wf_g + 2048;

  // Tw/Tx zero-padded B-frags: b[i<4] = T[4q+i][tl], b[4..7] = 0
  s16x8 twb8, txb8;
  {
    frag8 a, c;
    a.u[0] = pack2(pw[(4 * q + 0) * 16 + tl], pw[(4 * q + 1) * 16 + tl]);
    a.u[1] = pack2(pw[(4 * q + 2) * 16 + tl], pw[(4 * q + 3) * 16 + tl]);
    a.u[2] = 0u; a.u[3] = 0u;
    c.u[0] = pack2(px[(4 * q + 0) * 16 + tl], px[(4 * q + 1) * 16 + tl]);
    c.u[1] = pack2(px[(4 * q + 2) * 16 + tl], px[(4 * q + 3) * 16 + tl]);
    c.u[2] = 0u; c.u[3] = 0u;
    twb8 = a.s8; txb8 = c.s8;
  }

  s16x8 f2 = {0, 0, 0, 0, 0, 0, 0, 0};   // ones in k-rows 0,1 (base column)
  if (q == 0) { f2[0] = (short)0x3F80; f2[1] = (short)0x3F80; }

  s16x8 ones8;                            // all-ones B (sum collapser)
  {
    frag8 o;
    o.u[0] = 0x3F803F80u; o.u[1] = 0x3F803F80u;
    o.u[2] = 0x3F803F80u; o.u[3] = 0x3F803F80u;
    ones8 = o.s8;
  }

  f32x4 p = {0.f, 0.f, 0.f, 0.f};        // V in D-layout; alpha0 = delta(0,0)
  if (j == 0) p[0] = 1.f;

  const int len = lengths[b];
  const int* ybase = seq + (size_t)b * NT * ND;

  int4 ya0, ya1, yb0, yb1;
  {
    const int* yr = ybase + (size_t)tl * ND + 8 * q;
    const int4* pp  = (const int4*)yr;
    const int4* pp2 = (const int4*)(yr + 32);
    ya0 = pp[0]; ya1 = pp[1]; yb0 = pp2[0]; yb1 = pp2[1];
  }

  float L2 = 0.f, Ls = 0.f, R = 0.f;
  const f32x4 z4 = {0.f, 0.f, 0.f, 0.f};

  for (int t0 = 0; t0 < len; t0 += 16) {
    union { s16x8 s; unsigned u[4]; } f0u, f1u;
    f0u.u[0] = (ya0.x ? 0x3F80u : 0u) | (ya0.y ? 0x3F800000u : 0u);
    f0u.u[1] = (ya0.z ? 0x3F80u : 0u) | (ya0.w ? 0x3F800000u : 0u);
    f0u.u[2] = (ya1.x ? 0x3F80u : 0u) | (ya1.y ? 0x3F800000u : 0u);
    f0u.u[3] = (ya1.z ? 0x3F80u : 0u) | (ya1.w ? 0x3F800000u : 0u);
    f1u.u[0] = (yb0.x ? 0x3F80u : 0u) | (yb0.y ? 0x3F800000u : 0u);
    f1u.u[1] = (yb0.z ? 0x3F80u : 0u) | (yb0.w ? 0x3F800000u : 0u);
    f1u.u[2] = (yb1.x ? 0x3F80u : 0u) | (yb1.y ? 0x3F800000u : 0u);
    f1u.u[3] = (yb1.z ? 0x3F80u : 0u) | (yb1.w ? 0x3F800000u : 0u);
    const s16x8 f0 = f0u.s, f1 = f1u.s;

    if (t0 + 16 < len) {   // prefetch next chunk's y under compute
      const int* yr = ybase + (size_t)(t0 + 16 + tl) * ND + 8 * q;
      const int4* pp  = (const int4*)yr;
      const int4* pp2 = (const int4*)(yr + 32);
      ya0 = pp[0]; ya1 = pp[1]; yb0 = pp2[0]; yb1 = pp2[1];
    }

    // ---- emission: G = exp2(E - R) incl. base, f32, 3 MFMAs/st ----
#pragma unroll
    for (int st = 0; st < 16; ++st) {
      f32x4 acc = MFMA32(w2_g[st * 64 + j], f2, z4);
      acc = MFMA32(wf_g[(2 * st + 0) * 64 + j], f0, acc);
      acc = MFMA32(wf_g[(2 * st + 1) * 64 + j], f1, acc);
      f32x4 G;
      G[0] = EXP2F(fminf(acc[0] - R, 80.f));
      G[1] = EXP2F(fminf(acc[1] - R, 80.f));
      G[2] = EXP2F(fminf(acc[2] - R, 80.f));
      G[3] = EXP2F(fminf(acc[3] - R, 80.f));
      e_w[tl * 64 + ((st * 4 + q) ^ tl)] = G;
    }

    // ---- recursion: register-only MFMA chain; no exp2/unpack/cross-lane ----
    const int nsteps = (len - t0 < 16) ? (len - t0) : 16;
    float LsC = 0.f;
    f32x4 gv = e_w[j];            // it=0 slot (j ^ 0 = j)
    for (int it = 0; it < nsteps; ++it) {
      const f32x4 g = gv;
      const int itn = (it + 1) & 15;
      gv = e_w[itn * 64 + (j ^ itn)];          // prefetch next step
      s16x8 vb = pack8t(p);                    // D-of-prev reused as A = V^T
      f32x4 P  = MFMA32(vb, twb8, z4);         // P  = V^T * Tw
      f32x4 S1 = MFMA32(vb, ones8, z4);        // row sums
      f32x4 U  = MFMA32(pack8t(P), txb8, z4);  // U  = Tw^T V Tx
      f32x4 S2 = MFMA32(pack8t(S1), ones8, z4);// grand total (mass of p_prev)
      const float s   = fmaxf(S2[0], 1e-30f);
      const float inv = RCPF(s);
      LsC += LOG2F(s);
      f32x4 pn;
      pn[0] = (U[0] * inv) * g[0];             // U*inv <= O(1); * G bounded
      pn[1] = (U[1] * inv) * g[1];
      pn[2] = (U[2] * inv) * g[2];
      pn[3] = (U[3] * inv) * g[3];
      p = pn;
    }
    L2 += (float)nsteps * R;                    // applied shift accounting
    Ls += LsC;
    R  += LsC * 0.0625f;                        // track typical emission scale
  }
  // final total of p via ones-MFMA
  {
    f32x4 F1 = MFMA32(pack8t(p), ones8, z4);
    f32x4 F2 = MFMA32(pack8t(F1), ones8, z4);
    float sf = fmaxf(F2[0], 1e-35f);
    float L = (L2 + Ls + LOG2F(sf)) * 0.6931471805599453f;
    if (j == 0) partials[b] = L;
  }
}

// ---------------------------------------------------------------------------
// Round-1 fallback (block per sequence) for small workspace.
// ---------------------------------------------------------------------------
__global__ __launch_bounds__(256, 3) void fhmm_fwd1(
    const int* __restrict__ seq, const int* __restrict__ lengths,
    const float* __restrict__ pw, const float* __restrict__ px,
    const float* __restrict__ py, float* __restrict__ partials,
    float* __restrict__ out)
{
  const int b = blockIdx.x, tid = threadIdx.x;
  const int wp = tid >> 4, xc = tid & 15;
  float Twc[16], Txc[16], W[64], base = 0.f;
#pragma unroll
  for (int w = 0; w < 16; ++w) Twc[w] = pw[w * 16 + wp];
#pragma unroll
  for (int x = 0; x < 16; ++x) Txc[x] = px[x * 16 + xc];
#pragma unroll
  for (int d = 0; d < 64; ++d) {
    float pv = py[tid * 64 + d];
    W[d] = logf(pv) - log1pf(-pv);
    base += log1pf(-pv);
  }
  __shared__ __align__(16) float yf[64];
  __shared__ __align__(16) float v_s[256];
  __shared__ __align__(16) float tmp_s[256];
  __shared__ float red[8];
  const int len = lengths[b];
  const int* yb = seq + (size_t)b * (NT * ND);
  v_s[tid] = (tid == 0) ? 1.f : 0.f;
  float L = 0.f, ynext = 0.f;
  if (tid < 64) ynext = (float)yb[tid];
  for (int t = 0; t < len; ++t) {
    if (tid < 64) yf[tid] = ynext;
    __syncthreads();
    if (tid < 64 && (t + 1) < len) ynext = (float)yb[(t + 1) * ND + tid];
    float e0 = base, e1 = 0.f, e2 = 0.f, e3 = 0.f;
    const float4* y4p = (const float4*)yf;
#pragma unroll
    for (int i = 0; i < 16; ++i) {
      float4 y4 = y4p[i];
      e0 = fmaf(y4.x, W[4 * i + 0], e0); e1 = fmaf(y4.y, W[4 * i + 1], e1);
      e2 = fmaf(y4.z, W[4 * i + 2], e2); e3 = fmaf(y4.w, W[4 * i + 3], e3);
    }
    float e = (e0 + e1) + (e2 + e3);
    float s1a = 0.f, s1b = 0.f;
#pragma unroll
    for (int w = 0; w < 16; w += 2) {
      s1a = fmaf(Twc[w], v_s[w * 16 + xc], s1a);
      s1b = fmaf(Twc[w + 1], v_s[(w + 1) * 16 + xc], s1b);
    }
    tmp_s[tid] = s1a + s1b;
    float mm = e;
#pragma unroll
    for (int off = 32; off; off >>= 1) mm = fmaxf(mm, __shfl_xor(mm, off));
    if ((tid & 63) == 0) red[tid >> 6] = mm;
    __syncthreads();
    mm = fmaxf(fmaxf(red[0], red[1]), fmaxf(red[2], red[3]));
    float q0 = 0.f, q1 = 0.f;
    const float4* t4p = (const float4*)(tmp_s + wp * 16);
#pragma unroll
    for (int i = 0; i < 4; ++i) {
      float4 t4 = t4p[i];
      q0 = fmaf(t4.x, Txc[4 * i + 0], q0); q1 = fmaf(t4.y, Txc[4 * i + 1], q1);
      q0 = fmaf(t4.z, Txc[4 * i + 2], q0); q1 = fmaf(t4.w, Txc[4 * i + 3], q1);
    }
    float val = (q0 + q1) * __expf(e - mm);
    float s = val;
#pragma unroll
    for (int off = 32; off; off >>= 1) s += __shfl_xor(s, off);
    if ((tid & 63) == 0) red[4 + (tid >> 6)] = s;
    __syncthreads();
    s = (red[4] + red[5]) + (red[6] + red[7]);
    L += __logf(s) + mm;
    v_s[tid] = val * (1.0f / s);
  }
  if (partials) { if (tid == 0) partials[b] = L; }
  else { if (tid == 0) atomicAdd(out, L); }
}

// ---------------------------------------------------------------------------
// Finalize: deterministic tree-sum of per-sequence LLs + priors.
// ---------------------------------------------------------------------------
__global__ void fhmm_finalize(const float* __restrict__ partials,
                              const float* __restrict__ pw,
                              const float* __restrict__ px,
                              const float* __restrict__ py,
                              float* __restrict__ out)
{
  const int tid = threadIdx.x;
  float a = 0.f;
  if (partials) {
#pragma unroll
    for (int i = 0; i < 8; ++i) a += partials[tid + 256 * i];
  }
  {
    int i = tid >> 4, j = tid & 15;
    if (i != j) a += -0.9f * (logf(pw[tid]) + logf(px[tid]));
  }
  for (int k = 0; k < 64; ++k) {
    float p = py[tid * 64 + k];
    a += -0.9f * logf(p) - 0.1f * log1pf(-p);
  }
  __shared__ float red[256];
  red[tid] = a;
  __syncthreads();
  for (int s = 128; s > 0; s >>= 1) {
    if (tid < s) red[tid] += red[tid + s];
    __syncthreads();
  }
  if (tid == 0) {
    const float cst =
        2.f * (16.f * 0.2846828704729192f - 240.f * 2.2527126517342055f)
        - (2.2527126517342055f + 0.0663762397347443f) * 16384.f;
    out[0] = red[0] + cst;
  }
}

extern "C" void kernel_launch(void* const* d_in, const int* in_sizes, int n_in,
                              void* d_out, int out_size, void* d_ws, size_t ws_size,
                              hipStream_t stream) {
  const int*   seq = (const int*)d_in[0];
  const int*   len = (const int*)d_in[1];
  const float* pw  = (const float*)d_in[2];
  const float* px  = (const float*)d_in[3];
  const float* py  = (const float*)d_in[4];
  float*       out = (float*)d_out;

  const size_t NEED = 65536;  // 32K wfrag + 16K base + 8K partials + 8K perm
  if (ws_size >= NEED) {
    unsigned short* wf = (unsigned short*)d_ws;
    float* partials = (float*)((char*)d_ws + 49152);
    int*   perm     = (int*)((char*)d_ws + 57344);
    fhmm_init_sort<<<13, 256, 0, stream>>>(py, len, wf, partials, perm);
    fhmm_fwd2<<<512, 256, 0, stream>>>(seq, len, pw, px, (const void*)wf, perm, partials);
    fhmm_finalize<<<1, 256, 0, stream>>>(partials, pw, px, py, out);
  } else if (ws_size >= NB * sizeof(float)) {
    float* partials = (float*)d_ws;
    fhmm_fwd1<<<NB, 256, 0, stream>>>(seq, len, pw, px, py, partials, out);
    fhmm_finalize<<<1, 256, 0, stream>>>(partials, pw, px, py, out);
  } else {
    fhmm_finalize<<<1, 256, 0, stream>>>(nullptr, pw, px, py, out);
    fhmm_fwd1<<<NB, 256, 0, stream>>>(seq, len, pw, px, py, nullptr, out);
  }
}